// Round 8
// baseline (165.287 us; speedup 1.0000x reference)
//
#include <hip/hip_runtime.h>
#include <math.h>

// Problem constants (fixed by setup_inputs)
#define BB    8
#define DD    64
#define NPIX  32768
#define KK    19
#define PP    5
#define KP    95
#define NR    160   // padded rows: 19 k-groups x 8 slots + 8 pad = 10 MFMA tiles

typedef _Float16 half8  __attribute__((ext_vector_type(8)));
typedef __fp16   half2t __attribute__((ext_vector_type(2)));   // cvt_pkrtz return type
typedef float    f32x4  __attribute__((ext_vector_type(4)));

union H8 { half8 v; half2t p[4]; };

// ---------------------------------------------------------------------------
// Prep: padded-group coefficient table. Row r = 8k + p (k = r>>3, p = r&7):
//   p < 5: real component j = 5k+p -> k-interleaved fp16 coeffs
//          C[r][2d] = mu_n*inv2, C[r][2d+1] = -0.5*inv2 ; cstp[r] = log-norm
//   else : zero row, cstp[r] = -3e38 (never wins the max)
//   r==159 additionally computes scal = {sum(w^2), sum(w*b), sum(b^2)}.
// ---------------------------------------------------------------------------
__global__ __launch_bounds__(64) void gmm_prep(
        const float* __restrict__ means, const float* __restrict__ diag,
        const float* __restrict__ feat_w, const float* __restrict__ feat_b,
        _Float16* __restrict__ Cp, float* __restrict__ cstp,
        float* __restrict__ scal) {
    int r = blockIdx.x;        // 0..159
    int d = threadIdx.x;       // 0..63
    int k = r >> 3, p = r & 7;
    if (k < KK && p < PP) {
        int j = 5 * k + p;
        float mu = means[j * DD + d];
        float sc = diag[j * DD + d];
        float ss = mu * mu;
        #pragma unroll
        for (int off = 32; off; off >>= 1) ss += __shfl_xor(ss, off);
        float inv = 1.f / fmaxf(sqrtf(ss), 1e-12f);
        float mn = mu * inv;
        float i2 = 1.f / (sc * sc);
        Cp[r * 128 + 2 * d]     = (_Float16)(mn * i2);
        Cp[r * 128 + 2 * d + 1] = (_Float16)(-0.5f * i2);
        float c1 = mn * mn * i2;
        float c2 = logf(sc);
        #pragma unroll
        for (int off = 32; off; off >>= 1) {
            c1 += __shfl_xor(c1, off);
            c2 += __shfl_xor(c2, off);
        }
        if (d == 0) cstp[r] = -0.5f * c1 - c2 - 58.8120661251f; // 32*ln(2*pi)
    } else {
        Cp[r * 128 + 2 * d]     = (_Float16)0.f;
        Cp[r * 128 + 2 * d + 1] = (_Float16)0.f;
        if (d == 0) cstp[r] = -3.0e38f;
        if (r == NR - 1) {
            float w = feat_w[d], b = feat_b[d];
            float s0 = w * w, s1 = w * b, s2 = b * b;
            #pragma unroll
            for (int off = 32; off; off >>= 1) {
                s0 += __shfl_xor(s0, off);
                s1 += __shfl_xor(s1, off);
                s2 += __shfl_xor(s2, off);
            }
            if (d == 0) { scal[0] = s0; scal[1] = s1; scal[2] = s2; }
        }
    }
}

// ---------------------------------------------------------------------------
// Main: 256 thr = 4 fully-independent waves, 32 px each (2 MFMA B-tiles).
// ZERO __shared__, ZERO barriers, no LDS logp transpose:
//   - padded 8-slot k-groups align group boundaries with the MFMA C layout:
//     lane (m15,q) reg rg holds row 16t+4q+rg; a k-group = quads {2qh,2qh+1}
//     -> max-over-P = 3 in-lane fmax + 1 shfl_xor(16).
//   - LN over K: lane tracks k=2t+qh across the 10 tiles; 1 shfl_xor(32)
//     completes the 19-term sums (partner lane holds the other parity).
//   - stores: q bit0 = px-tile, q bit1 = k-parity -> each (k,px) once.
//   u B-fragments built in registers (split-fp16 hi/lo via cvt_pkrtz);
//   C-fragments prefetched 1 tile ahead from the 40KB L1/L2-hot table.
// ---------------------------------------------------------------------------
__global__ __launch_bounds__(256, 2) void gmm_main(
        const float* __restrict__ bf,
        const float* __restrict__ feat_w, const float* __restrict__ feat_b,
        const float* __restrict__ mask_w, const float* __restrict__ mask_b,
        const _Float16* __restrict__ Cp, const float* __restrict__ cstp,
        const float* __restrict__ scal, float* __restrict__ out) {
    const int tid  = threadIdx.x;
    const int w    = tid >> 6;
    const int lane = tid & 63;
    const int m15  = lane & 15;
    const int q    = lane >> 4;
    const int bidx = blockIdx.x;
    const int b    = bidx >> 8;                        // 256 blocks per image
    const int n0   = ((bidx & 255) << 7) + (w << 5);   // wave's 32 pixels

    // ---- global x loads: 2 px-tiles x lane's 16 d's ----
    const float* xp = bf + (size_t)b * (DD * NPIX) + n0 + m15;
    float xs0[16], xs1[16];
    #pragma unroll
    for (int ks = 0; ks < 4; ++ks)
        #pragma unroll
        for (int i = 0; i < 4; ++i) {
            const size_t off = (size_t)(ks * 16 + q * 4 + i) * NPIX;
            xs0[ks * 4 + i] = xp[off];
            xs1[ks * 4 + i] = xp[off + 16];
        }

    float4 wv[4], bv[4];
    #pragma unroll
    for (int ks = 0; ks < 4; ++ks) {
        wv[ks] = *(const float4*)(feat_w + ks * 16 + q * 4);
        bv[ks] = *(const float4*)(feat_b + ks * 16 + q * 4);
    }

    // ---- moments for both pixels; combine the 4 q-lanes per px ----
    float S1a = 0.f, S2a = 0.f, S3a = 0.f, S4a = 0.f, S5a = 0.f;
    float S1b = 0.f, S2b = 0.f, S3b = 0.f, S4b = 0.f, S5b = 0.f;
    #pragma unroll
    for (int ks = 0; ks < 4; ++ks)
        #pragma unroll
        for (int i = 0; i < 4; ++i) {
            float wd = ((const float*)&wv[ks])[i];
            float bd = ((const float*)&bv[ks])[i];
            float xa = xs0[ks * 4 + i], xb = xs1[ks * 4 + i];
            float ta = wd * xa, tb = wd * xb;
            S1a += xa; S2a = fmaf(xa, xa, S2a); S3a = fmaf(ta, ta, S3a);
            S4a = fmaf(ta, wd, S4a); S5a = fmaf(ta, bd, S5a);
            S1b += xb; S2b = fmaf(xb, xb, S2b); S3b = fmaf(tb, tb, S3b);
            S4b = fmaf(tb, wd, S4b); S5b = fmaf(tb, bd, S5b);
        }
    S1a += __shfl_xor(S1a, 16); S1a += __shfl_xor(S1a, 32);
    S2a += __shfl_xor(S2a, 16); S2a += __shfl_xor(S2a, 32);
    S3a += __shfl_xor(S3a, 16); S3a += __shfl_xor(S3a, 32);
    S4a += __shfl_xor(S4a, 16); S4a += __shfl_xor(S4a, 32);
    S5a += __shfl_xor(S5a, 16); S5a += __shfl_xor(S5a, 32);
    S1b += __shfl_xor(S1b, 16); S1b += __shfl_xor(S1b, 32);
    S2b += __shfl_xor(S2b, 16); S2b += __shfl_xor(S2b, 32);
    S3b += __shfl_xor(S3b, 16); S3b += __shfl_xor(S3b, 32);
    S4b += __shfl_xor(S4b, 16); S4b += __shfl_xor(S4b, 32);
    S5b += __shfl_xor(S5b, 16); S5b += __shfl_xor(S5b, 32);

    const float W2 = scal[0], WB = scal[1], B2 = scal[2];
    float al0, e0, f0, al1, e1, f1;
    {
        float mu  = S1a * (1.f / 64.f);
        float var = fmaxf(S2a * (1.f / 64.f) - mu * mu, 0.f);
        float r   = rsqrtf(var + 1e-5f);
        float Sy2 = r * r * (S3a - 2.f * mu * S4a + mu * mu * W2)
                  + 2.f * r * (S5a - mu * WB) + B2;
        float invn = 1.f / fmaxf(sqrtf(fmaxf(Sy2, 0.f)), 1e-12f);
        al0 = invn * r; e0 = invn; f0 = -al0 * mu;
    }
    {
        float mu  = S1b * (1.f / 64.f);
        float var = fmaxf(S2b * (1.f / 64.f) - mu * mu, 0.f);
        float r   = rsqrtf(var + 1e-5f);
        float Sy2 = r * r * (S3b - 2.f * mu * S4b + mu * mu * W2)
                  + 2.f * r * (S5b - mu * WB) + B2;
        float invn = 1.f / fmaxf(sqrtf(fmaxf(Sy2, 0.f)), 1e-12f);
        al1 = invn * r; e1 = invn; f1 = -al1 * mu;
    }

    // ---- build split-fp16 u B-fragments in registers (packed cvt) ----
    H8 Uh[2][4], Ul[2][4];
    #pragma unroll
    for (int ks = 0; ks < 4; ++ks) {
        #pragma unroll
        for (int i = 0; i < 4; ++i) {
            float wd = ((const float*)&wv[ks])[i];
            float bd = ((const float*)&bv[ks])[i];
            float c0 = fmaf(f0, wd, e0 * bd);
            float c1 = fmaf(f1, wd, e1 * bd);
            float u0 = fmaf(al0, wd * xs0[ks * 4 + i], c0);
            float u1 = fmaf(al1, wd * xs1[ks * 4 + i], c1);
            float q0 = u0 * u0, q1 = u1 * u1;
            half2t h0 = __builtin_amdgcn_cvt_pkrtz(u0, q0);   // [u, usq] hi
            half2t h1 = __builtin_amdgcn_cvt_pkrtz(u1, q1);
            half2t l0 = __builtin_amdgcn_cvt_pkrtz(u0 - (float)h0[0], q0 - (float)h0[1]);
            half2t l1 = __builtin_amdgcn_cvt_pkrtz(u1 - (float)h1[0], q1 - (float)h1[1]);
            Uh[0][ks].p[i] = h0; Ul[0][ks].p[i] = l0;
            Uh[1][ks].p[i] = h1; Ul[1][ks].p[i] = l1;
        }
    }

    // ---- j-loop: 10 comp-tiles x 16 MFMAs; per-tile in-register group-max --
    float mv0[10], mv1[10];
    const _Float16* cb = Cp + (size_t)m15 * 128 + q * 8;   // A row = 16t + m15
    half8 Ac[4];
    #pragma unroll
    for (int ks = 0; ks < 4; ++ks) Ac[ks] = *(const half8*)(cb + ks * 32);
    float4 cc = *(const float4*)(cstp + 4 * q);            // row = 16t+4q+rg

    #pragma unroll 2
    for (int t = 0; t < 10; ++t) {
        half8 An[4];
        float4 cn;
        if (t < 9) {
            const _Float16* nb = cb + (size_t)(16 * (t + 1)) * 128;
            #pragma unroll
            for (int ks = 0; ks < 4; ++ks) An[ks] = *(const half8*)(nb + ks * 32);
            cn = *(const float4*)(cstp + 16 * (t + 1) + 4 * q);
        }
        f32x4 a0 = {0.f, 0.f, 0.f, 0.f}, a1 = a0;
        #pragma unroll
        for (int ks = 0; ks < 4; ++ks) {
            a0 = __builtin_amdgcn_mfma_f32_16x16x32_f16(Ac[ks], Uh[0][ks].v, a0, 0, 0, 0);
            a1 = __builtin_amdgcn_mfma_f32_16x16x32_f16(Ac[ks], Uh[1][ks].v, a1, 0, 0, 0);
        }
        #pragma unroll
        for (int ks = 0; ks < 4; ++ks) {
            a0 = __builtin_amdgcn_mfma_f32_16x16x32_f16(Ac[ks], Ul[0][ks].v, a0, 0, 0, 0);
            a1 = __builtin_amdgcn_mfma_f32_16x16x32_f16(Ac[ks], Ul[1][ks].v, a1, 0, 0, 0);
        }
        // in-lane max over this lane's 4 rows (all in one 8-slot k-group)
        float c0 = fmaxf(fmaxf(a0[0] + cc[0], a0[1] + cc[1]),
                         fmaxf(a0[2] + cc[2], a0[3] + cc[3]));
        float c1 = fmaxf(fmaxf(a1[0] + cc[0], a1[1] + cc[1]),
                         fmaxf(a1[2] + cc[2], a1[3] + cc[3]));
        // combine partner quad (rows 4(q^1)..+3 of the same group)
        c0 = fmaxf(c0, __shfl_xor(c0, 16));
        c1 = fmaxf(c1, __shfl_xor(c1, 16));
        mv0[t] = c0;   // group-max for k = 2t + qh, px-tile 0
        mv1[t] = c1;   // same, px-tile 1
        if (t < 9) {
            #pragma unroll
            for (int ks = 0; ks < 4; ++ks) Ac[ks] = An[ks];
            cc = cn;
        }
    }

    // ---- epilogue: all in registers + 2 shfl rounds ----
    const int qh = (lane >> 5) & 1;     // k-parity this lane holds (k = 2t+qh)
    float S0 = 0.f, S1 = 0.f;
    #pragma unroll
    for (int t = 0; t < 10; ++t) {
        if (2 * t + qh < KK) { S0 += mv0[t]; S1 += mv1[t]; }
    }
    S0 += __shfl_xor(S0, 32);           // partner holds the other parity
    S1 += __shfl_xor(S1, 32);
    const float mum0 = S0 * (1.f / 19.f);
    const float mum1 = S1 * (1.f / 19.f);
    float V0 = 0.f, V1 = 0.f;
    #pragma unroll
    for (int t = 0; t < 10; ++t) {
        if (2 * t + qh < KK) {
            float d0 = mv0[t] - mum0; V0 = fmaf(d0, d0, V0);
            float d1 = mv1[t] - mum1; V1 = fmaf(d1, d1, V1);
        }
    }
    V0 += __shfl_xor(V0, 32);
    V1 += __shfl_xor(V1, 32);
    const float rm0 = rsqrtf(V0 * (1.f / 19.f) + 1e-5f);
    const float rm1 = rsqrtf(V1 * (1.f / 19.f) + 1e-5f);

    // q bit0 picks the px-tile; q bit1 (qh) picks the k-parity
    const int ht   = q & 1;
    const float mum = ht ? mum1 : mum0;
    const float rm  = ht ? rm1  : rm0;
    float* op = out + (size_t)b * (KK * NPIX) + n0 + ht * 16 + m15;
    #pragma unroll
    for (int t = 0; t < 10; ++t) {
        const int k = 2 * t + qh;
        if (k < KK) {
            float v = ht ? mv1[t] : mv0[t];
            op[(size_t)k * NPIX] = (v - mum) * rm * mask_w[k] + mask_b[k];
        }
    }
}

extern "C" void kernel_launch(void* const* d_in, const int* in_sizes, int n_in,
                              void* d_out, int out_size, void* d_ws, size_t ws_size,
                              hipStream_t stream) {
    const float* base_feature = (const float*)d_in[0]; // [8, 64, 32768]
    const float* means        = (const float*)d_in[1]; // [19, 5, 64]
    const float* diagonal     = (const float*)d_in[2]; // [19, 5, 64]
    const float* feat_w       = (const float*)d_in[3]; // [64]
    const float* feat_b       = (const float*)d_in[4]; // [64]
    const float* mask_w       = (const float*)d_in[5]; // [19]
    const float* mask_b       = (const float*)d_in[6]; // [19]
    float* out = (float*)d_out;                        // [8, 19, 32768] fp32

    // ws layout: Cp[160*128] f16 (40960 B) | cstp[160] f32 | scal[3] f32
    _Float16* Cp = (_Float16*)d_ws;
    float* cstp  = (float*)(Cp + NR * 128);
    float* scal  = cstp + NR;

    gmm_prep<<<NR, 64, 0, stream>>>(means, diagonal, feat_w, feat_b, Cp, cstp, scal);

    gmm_main<<<(BB * NPIX) / 128, 256, 0, stream>>>(
        base_feature, feat_w, feat_b, mask_w, mask_b, Cp, cstp, scal, out);
}

// Round 9
// 152.513 us; speedup vs baseline: 1.0838x; 1.0838x over previous
//
#include <hip/hip_runtime.h>
#include <math.h>

// Problem constants (fixed by setup_inputs)
#define BB    8
#define DD    64
#define NPIX  32768
#define KK    19
#define PP    5
#define KP    95
#define NR    160   // padded rows: 19 k-groups x 8 slots + 8 pad = 10 MFMA tiles

typedef _Float16 half8  __attribute__((ext_vector_type(8)));
typedef __fp16   half2t __attribute__((ext_vector_type(2)));   // cvt_pkrtz return type
typedef float    f32x4  __attribute__((ext_vector_type(4)));

union H8 { half8 v; half2t p[4]; };

// ---------------------------------------------------------------------------
// Prep: padded-group coefficient table. Row r = 8k + p (k = r>>3, p = r&7):
//   p < 5: real component j = 5k+p -> k-interleaved fp16 coeffs
//          C[r][2d] = mu_n*inv2, C[r][2d+1] = -0.5*inv2 ; cstp[r] = log-norm
//   else : zero row, cstp[r] = -3e38 (never wins the max)
//   r==159 additionally computes scal = {sum(w^2), sum(w*b), sum(b^2)}.
// ---------------------------------------------------------------------------
__global__ __launch_bounds__(64) void gmm_prep(
        const float* __restrict__ means, const float* __restrict__ diag,
        const float* __restrict__ feat_w, const float* __restrict__ feat_b,
        _Float16* __restrict__ Cp, float* __restrict__ cstp,
        float* __restrict__ scal) {
    int r = blockIdx.x;        // 0..159
    int d = threadIdx.x;       // 0..63
    int k = r >> 3, p = r & 7;
    if (k < KK && p < PP) {
        int j = 5 * k + p;
        float mu = means[j * DD + d];
        float sc = diag[j * DD + d];
        float ss = mu * mu;
        #pragma unroll
        for (int off = 32; off; off >>= 1) ss += __shfl_xor(ss, off);
        float inv = 1.f / fmaxf(sqrtf(ss), 1e-12f);
        float mn = mu * inv;
        float i2 = 1.f / (sc * sc);
        Cp[r * 128 + 2 * d]     = (_Float16)(mn * i2);
        Cp[r * 128 + 2 * d + 1] = (_Float16)(-0.5f * i2);
        float c1 = mn * mn * i2;
        float c2 = logf(sc);
        #pragma unroll
        for (int off = 32; off; off >>= 1) {
            c1 += __shfl_xor(c1, off);
            c2 += __shfl_xor(c2, off);
        }
        if (d == 0) cstp[r] = -0.5f * c1 - c2 - 58.8120661251f; // 32*ln(2*pi)
    } else {
        Cp[r * 128 + 2 * d]     = (_Float16)0.f;
        Cp[r * 128 + 2 * d + 1] = (_Float16)0.f;
        if (d == 0) cstp[r] = -3.0e38f;
        if (r == NR - 1) {
            float w = feat_w[d], b = feat_b[d];
            float s0 = w * w, s1 = w * b, s2 = b * b;
            #pragma unroll
            for (int off = 32; off; off >>= 1) {
                s0 += __shfl_xor(s0, off);
                s1 += __shfl_xor(s1, off);
                s2 += __shfl_xor(s2, off);
            }
            if (d == 0) { scal[0] = s0; scal[1] = s1; scal[2] = s2; }
        }
    }
}

// ---------------------------------------------------------------------------
// Main: 256 thr = 4 fully-independent waves, 32 px each (2 MFMA B-tiles).
// ZERO __shared__, ZERO barriers. The j-loop is FULLY unrolled: round 8's
// "#pragma unroll 2" made mv0[t]/mv1[t] runtime-indexed register arrays ->
// 41 MB of scratch spill traffic (WRITE_SIZE 60 MB) -> scratch-latency-bound.
// Full unroll keeps them in registers.
//   - padded 8-slot k-groups align with MFMA C layout: lane (m15,q) reg rg
//     holds row 16t+4q+rg; group = quads {2qh,2qh+1} -> max-over-P is 3
//     in-lane fmax + 1 shfl_xor(16).
//   - LN over K: lane holds k=2t+qh; 1 shfl_xor(32) completes 19-term sums.
//   - stores: q bit0 = px-tile, q bit1 = k-parity -> each (k,px) once.
// ---------------------------------------------------------------------------
__global__ __launch_bounds__(256, 2) void gmm_main(
        const float* __restrict__ bf,
        const float* __restrict__ feat_w, const float* __restrict__ feat_b,
        const float* __restrict__ mask_w, const float* __restrict__ mask_b,
        const _Float16* __restrict__ Cp, const float* __restrict__ cstp,
        const float* __restrict__ scal, float* __restrict__ out) {
    const int tid  = threadIdx.x;
    const int w    = tid >> 6;
    const int lane = tid & 63;
    const int m15  = lane & 15;
    const int q    = lane >> 4;
    const int bidx = blockIdx.x;
    const int b    = bidx >> 8;                        // 256 blocks per image
    const int n0   = ((bidx & 255) << 7) + (w << 5);   // wave's 32 pixels

    // ---- global x loads: 2 px-tiles x lane's 16 d's ----
    const float* xp = bf + (size_t)b * (DD * NPIX) + n0 + m15;
    float xs0[16], xs1[16];
    #pragma unroll
    for (int ks = 0; ks < 4; ++ks)
        #pragma unroll
        for (int i = 0; i < 4; ++i) {
            const size_t off = (size_t)(ks * 16 + q * 4 + i) * NPIX;
            xs0[ks * 4 + i] = xp[off];
            xs1[ks * 4 + i] = xp[off + 16];
        }

    float4 wv[4], bv[4];
    #pragma unroll
    for (int ks = 0; ks < 4; ++ks) {
        wv[ks] = *(const float4*)(feat_w + ks * 16 + q * 4);
        bv[ks] = *(const float4*)(feat_b + ks * 16 + q * 4);
    }

    // ---- moments for both pixels; combine the 4 q-lanes per px ----
    float S1a = 0.f, S2a = 0.f, S3a = 0.f, S4a = 0.f, S5a = 0.f;
    float S1b = 0.f, S2b = 0.f, S3b = 0.f, S4b = 0.f, S5b = 0.f;
    #pragma unroll
    for (int ks = 0; ks < 4; ++ks)
        #pragma unroll
        for (int i = 0; i < 4; ++i) {
            float wd = ((const float*)&wv[ks])[i];
            float bd = ((const float*)&bv[ks])[i];
            float xa = xs0[ks * 4 + i], xb = xs1[ks * 4 + i];
            float ta = wd * xa, tb = wd * xb;
            S1a += xa; S2a = fmaf(xa, xa, S2a); S3a = fmaf(ta, ta, S3a);
            S4a = fmaf(ta, wd, S4a); S5a = fmaf(ta, bd, S5a);
            S1b += xb; S2b = fmaf(xb, xb, S2b); S3b = fmaf(tb, tb, S3b);
            S4b = fmaf(tb, wd, S4b); S5b = fmaf(tb, bd, S5b);
        }
    S1a += __shfl_xor(S1a, 16); S1a += __shfl_xor(S1a, 32);
    S2a += __shfl_xor(S2a, 16); S2a += __shfl_xor(S2a, 32);
    S3a += __shfl_xor(S3a, 16); S3a += __shfl_xor(S3a, 32);
    S4a += __shfl_xor(S4a, 16); S4a += __shfl_xor(S4a, 32);
    S5a += __shfl_xor(S5a, 16); S5a += __shfl_xor(S5a, 32);
    S1b += __shfl_xor(S1b, 16); S1b += __shfl_xor(S1b, 32);
    S2b += __shfl_xor(S2b, 16); S2b += __shfl_xor(S2b, 32);
    S3b += __shfl_xor(S3b, 16); S3b += __shfl_xor(S3b, 32);
    S4b += __shfl_xor(S4b, 16); S4b += __shfl_xor(S4b, 32);
    S5b += __shfl_xor(S5b, 16); S5b += __shfl_xor(S5b, 32);

    const float W2 = scal[0], WB = scal[1], B2 = scal[2];
    float al0, e0, f0, al1, e1, f1;
    {
        float mu  = S1a * (1.f / 64.f);
        float var = fmaxf(S2a * (1.f / 64.f) - mu * mu, 0.f);
        float r   = rsqrtf(var + 1e-5f);
        float Sy2 = r * r * (S3a - 2.f * mu * S4a + mu * mu * W2)
                  + 2.f * r * (S5a - mu * WB) + B2;
        float invn = 1.f / fmaxf(sqrtf(fmaxf(Sy2, 0.f)), 1e-12f);
        al0 = invn * r; e0 = invn; f0 = -al0 * mu;
    }
    {
        float mu  = S1b * (1.f / 64.f);
        float var = fmaxf(S2b * (1.f / 64.f) - mu * mu, 0.f);
        float r   = rsqrtf(var + 1e-5f);
        float Sy2 = r * r * (S3b - 2.f * mu * S4b + mu * mu * W2)
                  + 2.f * r * (S5b - mu * WB) + B2;
        float invn = 1.f / fmaxf(sqrtf(fmaxf(Sy2, 0.f)), 1e-12f);
        al1 = invn * r; e1 = invn; f1 = -al1 * mu;
    }

    // ---- build split-fp16 u B-fragments in registers (packed cvt) ----
    H8 Uh[2][4], Ul[2][4];
    #pragma unroll
    for (int ks = 0; ks < 4; ++ks) {
        #pragma unroll
        for (int i = 0; i < 4; ++i) {
            float wd = ((const float*)&wv[ks])[i];
            float bd = ((const float*)&bv[ks])[i];
            float c0 = fmaf(f0, wd, e0 * bd);
            float c1 = fmaf(f1, wd, e1 * bd);
            float u0 = fmaf(al0, wd * xs0[ks * 4 + i], c0);
            float u1 = fmaf(al1, wd * xs1[ks * 4 + i], c1);
            float q0 = u0 * u0, q1 = u1 * u1;
            half2t h0 = __builtin_amdgcn_cvt_pkrtz(u0, q0);   // [u, usq] hi
            half2t h1 = __builtin_amdgcn_cvt_pkrtz(u1, q1);
            half2t l0 = __builtin_amdgcn_cvt_pkrtz(u0 - (float)h0[0], q0 - (float)h0[1]);
            half2t l1 = __builtin_amdgcn_cvt_pkrtz(u1 - (float)h1[0], q1 - (float)h1[1]);
            Uh[0][ks].p[i] = h0; Ul[0][ks].p[i] = l0;
            Uh[1][ks].p[i] = h1; Ul[1][ks].p[i] = l1;
        }
    }

    // ---- j-loop: FULLY unrolled 10 tiles x 16 MFMAs; in-register group-max --
    float mv0[10], mv1[10];
    const _Float16* cb = Cp + (size_t)m15 * 128 + q * 8;   // A row = 16t + m15

    #pragma unroll
    for (int t = 0; t < 10; ++t) {
        const _Float16* cbt = cb + (size_t)(16 * t) * 128;
        half8 Ac[4];
        #pragma unroll
        for (int ks = 0; ks < 4; ++ks) Ac[ks] = *(const half8*)(cbt + ks * 32);
        float4 cc = *(const float4*)(cstp + 16 * t + 4 * q);  // row = 16t+4q+rg

        f32x4 a0 = {0.f, 0.f, 0.f, 0.f}, a1 = a0;
        #pragma unroll
        for (int ks = 0; ks < 4; ++ks) {
            a0 = __builtin_amdgcn_mfma_f32_16x16x32_f16(Ac[ks], Uh[0][ks].v, a0, 0, 0, 0);
            a1 = __builtin_amdgcn_mfma_f32_16x16x32_f16(Ac[ks], Uh[1][ks].v, a1, 0, 0, 0);
        }
        #pragma unroll
        for (int ks = 0; ks < 4; ++ks) {
            a0 = __builtin_amdgcn_mfma_f32_16x16x32_f16(Ac[ks], Ul[0][ks].v, a0, 0, 0, 0);
            a1 = __builtin_amdgcn_mfma_f32_16x16x32_f16(Ac[ks], Ul[1][ks].v, a1, 0, 0, 0);
        }
        // in-lane max over this lane's 4 rows (all in one 8-slot k-group)
        float c0 = fmaxf(fmaxf(a0[0] + cc[0], a0[1] + cc[1]),
                         fmaxf(a0[2] + cc[2], a0[3] + cc[3]));
        float c1 = fmaxf(fmaxf(a1[0] + cc[0], a1[1] + cc[1]),
                         fmaxf(a1[2] + cc[2], a1[3] + cc[3]));
        // combine partner quad (rows 4(q^1)..+3 of the same group)
        mv0[t] = fmaxf(c0, __shfl_xor(c0, 16));   // group-max, k = 2t+qh, tile 0
        mv1[t] = fmaxf(c1, __shfl_xor(c1, 16));   // same, px-tile 1
    }

    // ---- epilogue: all in registers + 2 shfl rounds ----
    const int qh = (lane >> 5) & 1;     // k-parity this lane holds (k = 2t+qh)
    float S0 = 0.f, S1 = 0.f;
    #pragma unroll
    for (int t = 0; t < 10; ++t) {
        if (2 * t + qh < KK) { S0 += mv0[t]; S1 += mv1[t]; }
    }
    S0 += __shfl_xor(S0, 32);           // partner holds the other parity
    S1 += __shfl_xor(S1, 32);
    const float mum0 = S0 * (1.f / 19.f);
    const float mum1 = S1 * (1.f / 19.f);
    float V0 = 0.f, V1 = 0.f;
    #pragma unroll
    for (int t = 0; t < 10; ++t) {
        if (2 * t + qh < KK) {
            float d0 = mv0[t] - mum0; V0 = fmaf(d0, d0, V0);
            float d1 = mv1[t] - mum1; V1 = fmaf(d1, d1, V1);
        }
    }
    V0 += __shfl_xor(V0, 32);
    V1 += __shfl_xor(V1, 32);
    const float rm0 = rsqrtf(V0 * (1.f / 19.f) + 1e-5f);
    const float rm1 = rsqrtf(V1 * (1.f / 19.f) + 1e-5f);

    // q bit0 picks the px-tile; q bit1 (qh) picks the k-parity
    const int ht   = q & 1;
    const float mum = ht ? mum1 : mum0;
    const float rm  = ht ? rm1  : rm0;
    float* op = out + (size_t)b * (KK * NPIX) + n0 + ht * 16 + m15;
    #pragma unroll
    for (int t = 0; t < 10; ++t) {
        const int k = 2 * t + qh;
        if (k < KK) {
            float v = ht ? mv1[t] : mv0[t];
            op[(size_t)k * NPIX] = (v - mum) * rm * mask_w[k] + mask_b[k];
        }
    }
}

extern "C" void kernel_launch(void* const* d_in, const int* in_sizes, int n_in,
                              void* d_out, int out_size, void* d_ws, size_t ws_size,
                              hipStream_t stream) {
    const float* base_feature = (const float*)d_in[0]; // [8, 64, 32768]
    const float* means        = (const float*)d_in[1]; // [19, 5, 64]
    const float* diagonal     = (const float*)d_in[2]; // [19, 5, 64]
    const float* feat_w       = (const float*)d_in[3]; // [64]
    const float* feat_b       = (const float*)d_in[4]; // [64]
    const float* mask_w       = (const float*)d_in[5]; // [19]
    const float* mask_b       = (const float*)d_in[6]; // [19]
    float* out = (float*)d_out;                        // [8, 19, 32768] fp32

    // ws layout: Cp[160*128] f16 (40960 B) | cstp[160] f32 | scal[3] f32
    _Float16* Cp = (_Float16*)d_ws;
    float* cstp  = (float*)(Cp + NR * 128);
    float* scal  = cstp + NR;

    gmm_prep<<<NR, 64, 0, stream>>>(means, diagonal, feat_w, feat_b, Cp, cstp, scal);

    gmm_main<<<(BB * NPIX) / 128, 256, 0, stream>>>(
        base_feature, feat_w, feat_b, mask_w, mask_b, Cp, cstp, scal, out);
}